// Round 2
// baseline (789.642 us; speedup 1.0000x reference)
//
// HierarchicalPattern — rev9. R8 post-mortem: mask 452 µs, VALUBusy 62%,
// occupancy 43.6% (3.5 waves/SIMD) -> VALU-issue + register-pressure bound:
// acc[64 f32] + uv[64 u32] both live across the 32-trial bisection forces
// AGPR traffic; every trial re-reads all 64 uv. feat still ~300 µs on a
// 512-block grid (2 blocks/CU, 2 waves/SIMD) -> latency-starved.
// rev9: (1) mask bisection runs in the FLOAT domain directly on acc in place
// (u>=mid <=> sv>=uint_as_float(mid-1); sv = banned ? -1 : relu(s); exact tie
// test = bits(sv)==lo-1) -> uv array deleted, ~64 fewer live regs, hi0 =
// 0x7F800000, block-uniform early-break on interval width 1.
// (2) feat k-split (runtime 4/2/1 gated on ws_size) with deterministic
// partial buffers + ordered reduce kernel; LDS overlay (trans reuses xs|ws,
// 17.4 KiB) -> 2048 blocks, 8 blocks/CU, 8 waves/SIMD.
#include <hip/hip_runtime.h>
#include <hip/hip_fp16.h>
#include <cstdint>

#define SEQ 4096
#define NB 4
#define DMODEL 1024
#define ID 64
#define LW 16
#define GK 32
#define TQ 4

#define NEG_INF (-__builtin_inff())
#define MASKED4 0xFBFFFBFFu
#define FMAT (NB * SEQ * ID)          // floats per feature matrix (1M = 4 MiB)

__device__ __forceinline__ float2 h2f2(unsigned int u) {
    __half2 h = *reinterpret_cast<__half2*>(&u);
    return __half22float2(h);
}

// ---------------- Kernel 1: lf/gfT partials, k-split -------------------------
// grid 512*ksplit. bid: kp = bid>>9 (k-chunk), rest&1 = {lf, gfT}, rest>>1 =
// 64-row block. LDS overlay: trans reuses xs|ws (both 4352 floats) -> 17.4 KiB
// -> 8 blocks/CU. Partials are deterministic (sequential k within chunk;
// reduce sums chunks in fixed order).
__global__ __launch_bounds__(256)
void hp_feat_v9(const unsigned short* __restrict__ x,
                const unsigned short* __restrict__ Wl,
                const unsigned short* __restrict__ Wg,
                float* __restrict__ plf, float* __restrict__ pgf,
                int ksplit)
{
    __shared__ float pool[2 * 32 * 68];          // xs | ws, reused as trans
    float (*xs)[68] = (float(*)[68])pool;
    float (*ws)[68] = (float(*)[68])(pool + 32 * 68);
    float (*trans)[68] = (float(*)[68])pool;     // 64*68 == 2*32*68

    const int tid = threadIdx.x;
    const int rest = blockIdx.x & 511;
    const int kp = blockIdx.x >> 9;
    const int half = rest & 1;
    const long row0 = (long)(rest >> 1) * 64;
    const unsigned short* W = half ? Wg : Wl;
    const int tx = tid & 15, ty = tid >> 4;
    const int kw = DMODEL / ksplit;
    const int kbase = kp * kw;

    float acc[4][4];
#pragma unroll
    for (int r = 0; r < 4; r++)
#pragma unroll
        for (int c = 0; c < 4; c++) acc[r][c] = 0.f;

    for (int k0 = kbase; k0 < kbase + kw; k0 += 32) {
        {   // x tile: 64 rows x 32 k; 8 fp16 per thread
            int r = tid >> 2, c8 = (tid & 3) * 8;
            uint4 v = *(const uint4*)(x + (row0 + r) * DMODEL + k0 + c8);
            float2 f;
            f = h2f2(v.x); xs[c8 + 0][r] = f.x; xs[c8 + 1][r] = f.y;
            f = h2f2(v.y); xs[c8 + 2][r] = f.x; xs[c8 + 3][r] = f.y;
            f = h2f2(v.z); xs[c8 + 4][r] = f.x; xs[c8 + 5][r] = f.y;
            f = h2f2(v.w); xs[c8 + 6][r] = f.x; xs[c8 + 7][r] = f.y;
        }
        {   // W tile: 64 cols x 32 k
            int r = tid >> 2, c8 = (tid & 3) * 8;
            uint4 v = *(const uint4*)(W + (long)r * DMODEL + k0 + c8);
            float2 f;
            f = h2f2(v.x); ws[c8 + 0][r] = f.x; ws[c8 + 1][r] = f.y;
            f = h2f2(v.y); ws[c8 + 2][r] = f.x; ws[c8 + 3][r] = f.y;
            f = h2f2(v.z); ws[c8 + 4][r] = f.x; ws[c8 + 5][r] = f.y;
            f = h2f2(v.w); ws[c8 + 6][r] = f.x; ws[c8 + 7][r] = f.y;
        }
        __syncthreads();
#pragma unroll
        for (int kk = 0; kk < 32; kk++) {
            float4 a  = *(const float4*)&xs[kk][ty * 4];
            float4 bv = *(const float4*)&ws[kk][tx * 4];
            const float ar[4] = {a.x, a.y, a.z, a.w};
            const float bc[4] = {bv.x, bv.y, bv.z, bv.w};
#pragma unroll
            for (int r = 0; r < 4; r++)
#pragma unroll
                for (int c = 0; c < 4; c++)
                    acc[r][c] = fmaf(ar[r], bc[c], acc[r][c]);
        }
        __syncthreads();   // also protects the trans overlay below
    }

    float* lfp = plf + (long)kp * FMAT;
    float* gfp = pgf + (long)kp * FMAT;
    if (!half) {        // lf rows, row-major, coalesced float4
#pragma unroll
        for (int r = 0; r < 4; r++) {
            float4 st = make_float4(acc[r][0], acc[r][1], acc[r][2], acc[r][3]);
            *(float4*)(lfp + (row0 + ty * 4 + r) * ID + tx * 4) = st;
        }
    } else {            // gfT[b][col][s]: LDS transpose then coalesced stores
#pragma unroll
        for (int r = 0; r < 4; r++)
#pragma unroll
            for (int c = 0; c < 4; c++)
                trans[tx * 4 + c][ty * 4 + r] = acc[r][c];
        __syncthreads();
        const int b = (int)(row0 >> 12), s0 = (int)(row0 & 4095);
        const int col = tid >> 2, rs = (tid & 3) * 16;
        float* dst = gfp + ((long)b * ID + col) * SEQ + s0 + rs;
#pragma unroll
        for (int u = 0; u < 4; u++)
            *(float4*)(dst + 4 * u) = *(const float4*)&trans[col][rs + 4 * u];
    }
}

// ---------------- Kernel 1b: ordered partial reduce --------------------------
// ws layout: [plf p0..p(ks-1)][pgf p0..p(ks-1)], each FMAT floats. Sums
// chunks in fixed ascending order (deterministic); finals land in p0 slots.
__global__ __launch_bounds__(256)
void hp_reduce(float4* __restrict__ ws4, int ksplit)
{
    const int M = FMAT / 4;                       // 262144 float4 per matrix
    const int i = blockIdx.x * 256 + threadIdx.x; // 0 .. 2M-1
    const int ingf = i >= M;
    const long base = ingf ? (long)ksplit * M : 0;
    const int j = ingf ? i - M : i;
    float4 s = ws4[base + j];
#pragma unroll 1
    for (int p = 1; p < ksplit; p++) {
        float4 v = ws4[base + j + (long)p * M];
        s.x += v.x; s.y += v.y; s.z += v.z; s.w += v.w;
    }
    ws4[base + j] = s;
}

// ---------------- Kernel 2: TQ=4 queries per block ---------------------------
// Phase 1: outer-product scores (unchanged). Phase 2: bisection in FLOAT
// domain, in place on acc: sv = banned ? -1 : relu(s); u = bits(sv)+1 never
// materialized. u >= mid <=> sv >= uint_as_float(mid-1) (monotone on [0,inf);
// banned -1 < every threshold since lo >= 1 at convergence). Exact tie:
// bits(sv) == lo-1. hi0 = 0x7F800000 (scores finite); early-break when all 4
// intervals reach width 1 (block-uniform: lo/hi derive from shared tot).
// NB: thresholds can hit denormal range only if the 32nd score < 1e-38 —
// unreachable for these inputs (thousands of O(1) positive scores).
__global__ __launch_bounds__(256)
void hp_mask_v9(const float* __restrict__ lf, const float* __restrict__ gfT,
                unsigned short* __restrict__ out)
{
    __shared__ float qv[TQ][ID];
    __shared__ float lq[TQ][ID];
    __shared__ unsigned long long red[4][4];      // [slot][wave]; 4x u16 counts
    __shared__ unsigned int bitmap[TQ][SEQ / 32]; // 2 KiB selection bitmap
    __shared__ float lsc[TQ][LW];
    __shared__ unsigned short tm[256];            // rare tie path

    const int tid = threadIdx.x;
    const int lane = tid & 63, w = tid >> 6;
    const int bq = blockIdx.x;            // b*(SEQ/TQ) + qgroup
    const int b = bq >> 10;
    const int q0 = (bq & 1023) * TQ;
    const float* gTb = gfT + (long)b * ID * SEQ;
    const float* lfb = lf + (long)b * SEQ * ID;

    {   // qv[qi][d] = gfT[b][d][q0+qi]; lq from lf rows; zero bitmap
        int d = tid >> 2, qi = tid & 3;
        qv[qi][d] = gTb[(long)d * SEQ + q0 + qi];
        int qi2 = tid >> 6, d2 = tid & 63;
        lq[qi2][d2] = lfb[(long)(q0 + qi2) * ID + d2];
        ((unsigned int*)bitmap)[tid] = 0u;
        ((unsigned int*)bitmap)[tid + 256] = 0u;
    }
    __syncthreads();

    // ---- Phase 1: register-resident scores ----------------------------------
    float acc[4][4][TQ];                  // [c][j][qi]
#pragma unroll
    for (int c = 0; c < 4; c++)
#pragma unroll
        for (int j = 0; j < 4; j++)
#pragma unroll
            for (int qi = 0; qi < TQ; qi++) acc[c][j][qi] = 0.f;

    for (int d = 0; d < ID; d++) {
        float qd[TQ];
#pragma unroll
        for (int qi = 0; qi < TQ; qi++) qd[qi] = qv[qi][d];  // uniform broadcast
        const float4* rowp = (const float4*)(gTb + (long)d * SEQ);
#pragma unroll
        for (int c = 0; c < 4; c++) {
            float4 kv = rowp[c * 256 + tid];
#pragma unroll
            for (int qi = 0; qi < TQ; qi++) {
                acc[c][0][qi] = fmaf(kv.x, qd[qi], acc[c][0][qi]);
                acc[c][1][qi] = fmaf(kv.y, qd[qi], acc[c][1][qi]);
                acc[c][2][qi] = fmaf(kv.z, qd[qi], acc[c][2][qi]);
                acc[c][3][qi] = fmaf(kv.w, qd[qi], acc[c][3][qi]);
            }
        }
    }

    // ---- Phase 2a: in-place keys: sv = banned ? -1 : relu(s) ----------------
#pragma unroll
    for (int c = 0; c < 4; c++)
#pragma unroll
        for (int j = 0; j < 4; j++) {
            const int k = 1024 * c + 4 * tid + j;
#pragma unroll
            for (int qi = 0; qi < TQ; qi++) {
                const int q = q0 + qi;
                const bool banned = (k <= q) && (k >= q - (LW - 1));
                acc[c][j][qi] = banned ? -1.0f : fmaxf(acc[c][j][qi], 0.f);
            }
        }

    // ---- Phase 2b: bisection for m32 in u-space, compares in float ----------
    unsigned int lo[TQ], hi[TQ];
#pragma unroll
    for (int qi = 0; qi < TQ; qi++) { lo[qi] = 0u; hi[qi] = 0x7F800000u; }

#pragma unroll 1
    for (int it = 0; it < 32; ++it) {
        unsigned int mid[TQ];
        unsigned long long pc = 0ull;
#pragma unroll
        for (int qi = 0; qi < TQ; qi++) {
            mid[qi] = lo[qi] + ((hi[qi] - lo[qi]) >> 1);
            const float tf = __uint_as_float(mid[qi] - 1u);
            int cnt = 0;
#pragma unroll
            for (int c = 0; c < 4; c++)
#pragma unroll
                for (int j = 0; j < 4; j++)
                    cnt += __popcll(__ballot(acc[c][j][qi] >= tf));
            pc |= (unsigned long long)(unsigned int)cnt << (16 * qi);
        }
        if (lane == 0) red[it & 1][w] = pc;
        __syncthreads();
        const unsigned long long tot = red[it & 1][0] + red[it & 1][1]
                                     + red[it & 1][2] + red[it & 1][3];
        int conv = 1;
#pragma unroll
        for (int qi = 0; qi < TQ; qi++) {
            const unsigned int cnt =
                (unsigned int)((tot >> (16 * qi)) & 0xFFFFull);
            if (cnt >= GK) lo[qi] = mid[qi]; else hi[qi] = mid[qi];
            conv &= (hi[qi] - lo[qi] <= 1u);
        }
        if (conv) break;                  // block-uniform (tot is shared)
    }

    // ---- Phase 2c: C1 = #{u > m32}, T = #{u == m32} -------------------------
    int C1[TQ], T[TQ], need[TQ];
    {
        unsigned long long pg = 0ull, pe = 0ull;
#pragma unroll
        for (int qi = 0; qi < TQ; qi++) {
            const float tg = __uint_as_float(lo[qi]);   // u>lo <=> sv>=float(lo)
            const unsigned int eb = lo[qi] - 1u;        // u==lo <=> bits(sv)==eb
            int cg = 0, ce = 0;
#pragma unroll
            for (int c = 0; c < 4; c++)
#pragma unroll
                for (int j = 0; j < 4; j++) {
                    const float v = acc[c][j][qi];
                    cg += __popcll(__ballot(v >= tg));
                    ce += __popcll(__ballot(__float_as_uint(v) == eb));
                }
            pg |= (unsigned long long)(unsigned int)cg << (16 * qi);
            pe |= (unsigned long long)(unsigned int)ce << (16 * qi);
        }
        if (lane == 0) { red[2][w] = pg; red[3][w] = pe; }
        __syncthreads();
        const unsigned long long tg = red[2][0] + red[2][1] + red[2][2] + red[2][3];
        const unsigned long long te = red[3][0] + red[3][1] + red[3][2] + red[3][3];
#pragma unroll
        for (int qi = 0; qi < TQ; qi++) {
            C1[qi]   = (int)((tg >> (16 * qi)) & 0xFFFFull);
            T[qi]    = (int)((te >> (16 * qi)) & 0xFFFFull);
            need[qi] = GK - C1[qi];           // >= 1; T >= need guaranteed
        }
    }

    // ---- Phase 2d: mark selections in bitmap --------------------------------
#pragma unroll
    for (int qi = 0; qi < TQ; qi++) {
        const bool allties = (T[qi] == need[qi]);
        const float tg = __uint_as_float(lo[qi]);
        const unsigned int eb = lo[qi] - 1u;
#pragma unroll
        for (int c = 0; c < 4; c++)
#pragma unroll
            for (int j = 0; j < 4; j++) {
                const float v = acc[c][j][qi];
                const bool sel_ = (v >= tg)
                                | (allties & (__float_as_uint(v) == eb));
                if (sel_) {
                    const int k = 1024 * c + 4 * tid + j;
                    atomicOr(&bitmap[qi][k >> 5], 1u << (k & 31));
                }
            }
    }

    // Rare exact-tie path: pick the `need` smallest-k ties ascending.
#pragma unroll 1
    for (int qi = 0; qi < TQ; qi++) {
        if (T[qi] > need[qi]) {
            const unsigned int eb = lo[qi] - 1u;
            unsigned int m16 = 0u;
#pragma unroll
            for (int c = 0; c < 4; c++)
#pragma unroll
                for (int j = 0; j < 4; j++)
                    if (__float_as_uint(acc[c][j][qi]) == eb)
                        m16 |= 1u << (c * 4 + j);
            tm[tid] = (unsigned short)m16;
            __syncthreads();
            if (tid == 0) {
                int taken = 0;
                for (int c = 0; c < 4 && taken < need[qi]; c++)
                    for (int t = 0; t < 256 && taken < need[qi]; t++) {
                        const unsigned int nib = ((unsigned int)tm[t] >> (c * 4)) & 15u;
                        for (int j = 0; j < 4 && taken < need[qi]; j++)
                            if ((nib >> j) & 1u) {
                                const int k = 1024 * c + 4 * t + j;
                                atomicOr(&bitmap[qi][k >> 5], 1u << (k & 31));
                                taken++;
                            }
                    }
            }
            __syncthreads();
        }
    }

    // ---- local window: 16 scores per query, stable top-ks -> bitmap ---------
    if (tid < TQ * LW) {
        int qi = tid >> 4, wnd = tid & 15;
        int q = q0 + qi;
        int win = q - (LW - 1) + wnd;
        float v = NEG_INF;
        if (win >= 0) {
            const float4* kr = (const float4*)(lfb + (long)win * ID);
            float s = 0.f;
#pragma unroll
            for (int d = 0; d < 16; d++) {
                float4 kvv = kr[d];
                const float4 qd = *(const float4*)&lq[qi][d * 4];
                s = fmaf(kvv.x, qd.x, s); s = fmaf(kvv.y, qd.y, s);
                s = fmaf(kvv.z, qd.z, s); s = fmaf(kvv.w, qd.w, s);
            }
            v = fmaxf(s, 0.f);
        }
        lsc[qi][wnd] = v;
    }
    __syncthreads();
    if (tid < TQ) {
        int qi = tid, q = q0 + qi;
        int L = (q + 1 < LW) ? q + 1 : LW;
        int ks = L / 5; if (ks < 1) ks = 1;   // == max(1, int(L*0.2))
        for (int t = 0; t < ks; t++) {
            float best = NEG_INF; int bi = 0;
            for (int wnd = 0; wnd < LW; wnd++) {
                float v = lsc[qi][wnd];
                if (v > best) { best = v; bi = wnd; }  // strict > keeps lowest idx
            }
            lsc[qi][bi] = NEG_INF;
            const int win = q - (LW - 1) + bi;
            atomicOr(&bitmap[qi][win >> 5], 1u << (win & 31));
        }
    }
    __syncthreads();

    // ---- output: single-pass fill from bitmap (each line written once) ------
    uint4* orow = (uint4*)(out + ((long)b * SEQ + q0) * SEQ);
#pragma unroll
    for (int i = 0; i < TQ * SEQ / 8 / 256; i++) {  // 8 iters, 2048 uint4
        const int li = i * 256 + tid;
        const int qi = li >> 9;          // 512 uint4 per row
        const int w8 = li & 511;         // cols 8*w8 .. 8*w8+7
        const unsigned int bits =
            (bitmap[qi][w8 >> 2] >> ((w8 & 3) * 8)) & 0xFFu;
        uint4 v;
        v.x = MASKED4 & ~(((bits &   1u) ? 0x0000FFFFu : 0u) |
                          ((bits &   2u) ? 0xFFFF0000u : 0u));
        v.y = MASKED4 & ~(((bits &   4u) ? 0x0000FFFFu : 0u) |
                          ((bits &   8u) ? 0xFFFF0000u : 0u));
        v.z = MASKED4 & ~(((bits &  16u) ? 0x0000FFFFu : 0u) |
                          ((bits &  32u) ? 0xFFFF0000u : 0u));
        v.w = MASKED4 & ~(((bits &  64u) ? 0x0000FFFFu : 0u) |
                          ((bits & 128u) ? 0xFFFF0000u : 0u));
        orow[li] = v;
    }
}

extern "C" void kernel_launch(void* const* d_in, const int* in_sizes, int n_in,
                              void* d_out, int out_size, void* d_ws, size_t ws_size,
                              hipStream_t stream) {
    const unsigned short* x  = (const unsigned short*)d_in[0];
    const unsigned short* Wl = (const unsigned short*)d_in[1];
    // d_in[2] = W_medium: dead in the reference — skipped.
    const unsigned short* Wg = (const unsigned short*)d_in[3];
    unsigned short* out = (unsigned short*)d_out;

    const size_t MB4 = (size_t)FMAT * sizeof(float);    // 4 MiB
    int ksplit = 1;
    if (ws_size >= 8 * MB4)      ksplit = 4;            // 32 MiB
    else if (ws_size >= 4 * MB4) ksplit = 2;            // 16 MiB

    float* plf = (float*)d_ws;                          // [ksplit][b][s][d]
    float* pgf = plf + (long)ksplit * FMAT;             // [ksplit][b][d][s]

    hp_feat_v9<<<512 * ksplit, 256, 0, stream>>>(x, Wl, Wg, plf, pgf, ksplit);
    if (ksplit > 1)
        hp_reduce<<<2 * FMAT / 4 / 256, 256, 0, stream>>>((float4*)d_ws, ksplit);
    hp_mask_v9<<<NB * SEQ / TQ, 256, 0, stream>>>(plf, pgf, out);
}

// Round 3
// 753.495 us; speedup vs baseline: 1.0480x; 1.0480x over previous
//
// HierarchicalPattern — rev10. R9 post-mortem: (a) ksplit never engaged
// (ws_size < 16 MiB -> feat unchanged ~292 µs; total arithmetic proves it);
// (b) mask REGRESSED 452->497 despite -64 live regs. VALUBusy*dur = ~22K
// VALU-instr/wave vs ~6K needed (3.4x), VGPR_Count 56 < the 64-reg live acc,
// occupancy pinned 44% -> allocator is shuffling acc through AGPR/scratch;
// every acc touch pays movement ops. rev10 attacks both structurally:
// FEAT: MFMA fp16 (inputs are fp16; products exact in f32). Guide-verified
// B^T pattern: A-frag = x rows, B-frag = W rows ([n][k] already), D col=l&15 /
// row=(l>>4)*4+reg -> gfT stores are natural float4 along s, NO LDS at all.
// Per wave 128 MFMA + 160 16B loads; HBM-bound ~25 µs floor.
// MASK: 512 thr x 8 keys/thread -> acc[2][4][4]=32 regs (live ~60 total),
// 8 waves/block. Bisection/tie/bitmap logic identical to R8/R9, re-indexed.
#include <hip/hip_runtime.h>
#include <hip/hip_fp16.h>
#include <cstdint>

#define SEQ 4096
#define NB 4
#define DMODEL 1024
#define ID 64
#define LW 16
#define GK 32
#define TQ 4

#define NEG_INF (-__builtin_inff())
#define MASKED4 0xFBFFFBFFu
#define FMAT (NB * SEQ * ID)          // floats per feature matrix (4 MiB)

typedef _Float16 f16x8 __attribute__((ext_vector_type(8)));
typedef float f32x4 __attribute__((ext_vector_type(4)));

// ---------------- Kernel 1: lf + gfT via MFMA (fp16 in, f32 out) -------------
// grid 512: bid&1 = {lf, gfT}, bid>>1 = 64-row block. 4 waves; wave w owns
// rows [w*16, w*16+16), all 64 cols (4 col-tiles), K=1024 in 32-steps.
// A-frag: lane l reads x[row0+w*16+(l&15)][k0+(l>>4)*8 ..+8)  (16B load)
// B-frag: lane l reads W[ct*16+(l&15)][k0+(l>>4)*8 ..+8)      (16B load)
// D: col = l&15 (d-index), row = (l>>4)*4+reg (s-index) -> gfT float4 along s.
__global__ __launch_bounds__(256)
void hp_feat_v10(const unsigned short* __restrict__ xu,
                 const unsigned short* __restrict__ Wlu,
                 const unsigned short* __restrict__ Wgu,
                 float* __restrict__ lf, float* __restrict__ gfT)
{
    const int tid = threadIdx.x;
    const int lane = tid & 63, w = tid >> 6;
    const int half = blockIdx.x & 1;
    const long row0 = (long)(blockIdx.x >> 1) * 64;
    const _Float16* xp = (const _Float16*)xu;
    const _Float16* Wp = (const _Float16*)(half ? Wgu : Wlu);

    const int lr = lane & 15;          // row-in-tile (A) / col-in-tile (B,D)
    const int kg = lane >> 4;          // k-group: k offset kg*8

    const _Float16* ap = xp + (row0 + w * 16 + lr) * DMODEL + kg * 8;
    const _Float16* bp = Wp + (long)lr * DMODEL + kg * 8;

    f32x4 acc[4];
#pragma unroll
    for (int ct = 0; ct < 4; ct++) acc[ct] = (f32x4){0.f, 0.f, 0.f, 0.f};

#pragma unroll 4
    for (int k0 = 0; k0 < DMODEL; k0 += 32) {
        f16x8 av = *(const f16x8*)(ap + k0);
#pragma unroll
        for (int ct = 0; ct < 4; ct++) {
            f16x8 bv = *(const f16x8*)(bp + (long)ct * 16 * DMODEL + k0);
            acc[ct] = __builtin_amdgcn_mfma_f32_16x16x32_f16(av, bv, acc[ct], 0, 0, 0);
        }
    }

    if (!half) {        // lf[s][d]: 16 lanes cover 16 consecutive d per row
#pragma unroll
        for (int ct = 0; ct < 4; ct++)
#pragma unroll
            for (int r = 0; r < 4; r++)
                lf[(row0 + w * 16 + kg * 4 + r) * ID + ct * 16 + lr] = acc[ct][r];
    } else {            // gfT[b][d][s]: float4 along s, no transpose needed
        const int bb = (int)(row0 >> 12), s0 = (int)(row0 & 4095);
#pragma unroll
        for (int ct = 0; ct < 4; ct++) {
            float4 st = make_float4(acc[ct][0], acc[ct][1], acc[ct][2], acc[ct][3]);
            *(float4*)(gfT + ((long)bb * ID + ct * 16 + lr) * SEQ
                           + s0 + w * 16 + kg * 4) = st;
        }
    }
}

// ---------------- Kernel 2: 512 threads, TQ=4 queries, 8 keys/thread ---------
// Phase 1: outer-product scores; thread t owns keys k = 2048c + 4t + j,
// c in {0,1}. acc[2][4][TQ] = 32 regs. Phase 2: float-domain bisection
// (R9 semantics, verified): sv = banned ? -1 : relu(s); u = bits(sv)+1;
// u>=mid <=> sv >= uint_as_float(mid-1); tie test bits(sv)==lo-1.
__global__ __launch_bounds__(512)
void hp_mask_v10(const float* __restrict__ lf, const float* __restrict__ gfT,
                 unsigned short* __restrict__ out)
{
    __shared__ float qv[TQ][ID];
    __shared__ float lq[TQ][ID];
    __shared__ unsigned long long red[4][8];      // [slot][wave]; 4x u16 counts
    __shared__ unsigned int bitmap[TQ][SEQ / 32]; // 2 KiB selection bitmap
    __shared__ float lsc[TQ][LW];
    __shared__ unsigned short tm[512];            // rare tie path

    const int tid = threadIdx.x;
    const int lane = tid & 63, w = tid >> 6;      // 8 waves
    const int bq = blockIdx.x;            // b*(SEQ/TQ) + qgroup
    const int b = bq >> 10;
    const int q0 = (bq & 1023) * TQ;
    const float* gTb = gfT + (long)b * ID * SEQ;
    const float* lfb = lf + (long)b * SEQ * ID;

    if (tid < 256) {   // qv[qi][d] = gfT[b][d][q0+qi]; lq from lf rows
        int d = tid >> 2, qi = tid & 3;
        qv[qi][d] = gTb[(long)d * SEQ + q0 + qi];
        int qi2 = tid >> 6, d2 = tid & 63;
        lq[qi2][d2] = lfb[(long)(q0 + qi2) * ID + d2];
    }
    ((unsigned int*)bitmap)[tid] = 0u;            // 512 words exactly
    __syncthreads();

    // ---- Phase 1: register-resident scores ----------------------------------
    float acc[2][4][TQ];                  // [c][j][qi]
#pragma unroll
    for (int c = 0; c < 2; c++)
#pragma unroll
        for (int j = 0; j < 4; j++)
#pragma unroll
            for (int qi = 0; qi < TQ; qi++) acc[c][j][qi] = 0.f;

    const float4* gT4 = (const float4*)gTb;
    for (int d = 0; d < ID; d++) {
        float qd[TQ];
#pragma unroll
        for (int qi = 0; qi < TQ; qi++) qd[qi] = qv[qi][d];  // uniform broadcast
        const float4 ka = gT4[(d << 10) + tid];
        const float4 kb = gT4[(d << 10) + 512 + tid];
#pragma unroll
        for (int qi = 0; qi < TQ; qi++) {
            acc[0][0][qi] = fmaf(ka.x, qd[qi], acc[0][0][qi]);
            acc[0][1][qi] = fmaf(ka.y, qd[qi], acc[0][1][qi]);
            acc[0][2][qi] = fmaf(ka.z, qd[qi], acc[0][2][qi]);
            acc[0][3][qi] = fmaf(ka.w, qd[qi], acc[0][3][qi]);
            acc[1][0][qi] = fmaf(kb.x, qd[qi], acc[1][0][qi]);
            acc[1][1][qi] = fmaf(kb.y, qd[qi], acc[1][1][qi]);
            acc[1][2][qi] = fmaf(kb.z, qd[qi], acc[1][2][qi]);
            acc[1][3][qi] = fmaf(kb.w, qd[qi], acc[1][3][qi]);
        }
    }

    // ---- Phase 2a: in-place keys: sv = banned ? -1 : relu(s) ----------------
#pragma unroll
    for (int c = 0; c < 2; c++)
#pragma unroll
        for (int j = 0; j < 4; j++) {
            const int k = 2048 * c + 4 * tid + j;
#pragma unroll
            for (int qi = 0; qi < TQ; qi++) {
                const int q = q0 + qi;
                const bool banned = (k <= q) && (k >= q - (LW - 1));
                acc[c][j][qi] = banned ? -1.0f : fmaxf(acc[c][j][qi], 0.f);
            }
        }

    // ---- Phase 2b: bisection for m32 in u-space, compares in float ----------
    unsigned int lo[TQ], hi[TQ];
#pragma unroll
    for (int qi = 0; qi < TQ; qi++) { lo[qi] = 0u; hi[qi] = 0x7F800000u; }

#pragma unroll 1
    for (int it = 0; it < 32; ++it) {
        unsigned long long pc = 0ull;
#pragma unroll
        for (int qi = 0; qi < TQ; qi++) {
            const unsigned int mid = lo[qi] + ((hi[qi] - lo[qi]) >> 1);
            const float tf = __uint_as_float(mid - 1u);
            int cnt = 0;
#pragma unroll
            for (int c = 0; c < 2; c++)
#pragma unroll
                for (int j = 0; j < 4; j++)
                    cnt += __popcll(__ballot(acc[c][j][qi] >= tf));
            pc |= (unsigned long long)(unsigned int)cnt << (16 * qi);
        }
        if (lane == 0) red[it & 1][w] = pc;
        __syncthreads();
        unsigned long long tot = 0ull;
#pragma unroll
        for (int ww = 0; ww < 8; ww++) tot += red[it & 1][ww];
        int conv = 1;
#pragma unroll
        for (int qi = 0; qi < TQ; qi++) {
            const unsigned int mid = lo[qi] + ((hi[qi] - lo[qi]) >> 1);
            const unsigned int cnt =
                (unsigned int)((tot >> (16 * qi)) & 0xFFFFull);
            if (cnt >= GK) lo[qi] = mid; else hi[qi] = mid;
            conv &= (hi[qi] - lo[qi] <= 1u);
        }
        if (conv) break;                  // block-uniform (tot is shared)
    }

    // ---- Phase 2c: C1 = #{u > m32}, T = #{u == m32} -------------------------
    int T[TQ], need[TQ];
    {
        unsigned long long pg = 0ull, pe = 0ull;
#pragma unroll
        for (int qi = 0; qi < TQ; qi++) {
            const float tg = __uint_as_float(lo[qi]);   // u>lo <=> sv>=float(lo)
            const unsigned int eb = lo[qi] - 1u;        // u==lo <=> bits(sv)==eb
            int cg = 0, ce = 0;
#pragma unroll
            for (int c = 0; c < 2; c++)
#pragma unroll
                for (int j = 0; j < 4; j++) {
                    const float v = acc[c][j][qi];
                    cg += __popcll(__ballot(v >= tg));
                    ce += __popcll(__ballot(__float_as_uint(v) == eb));
                }
            pg |= (unsigned long long)(unsigned int)cg << (16 * qi);
            pe |= (unsigned long long)(unsigned int)ce << (16 * qi);
        }
        if (lane == 0) { red[2][w] = pg; red[3][w] = pe; }
        __syncthreads();
        unsigned long long tg = 0ull, te = 0ull;
#pragma unroll
        for (int ww = 0; ww < 8; ww++) { tg += red[2][ww]; te += red[3][ww]; }
#pragma unroll
        for (int qi = 0; qi < TQ; qi++) {
            const int c1 = (int)((tg >> (16 * qi)) & 0xFFFFull);
            T[qi]    = (int)((te >> (16 * qi)) & 0xFFFFull);
            need[qi] = GK - c1;               // >= 1; T >= need guaranteed
        }
    }

    // ---- Phase 2d: mark selections in bitmap --------------------------------
#pragma unroll
    for (int qi = 0; qi < TQ; qi++) {
        const bool allties = (T[qi] == need[qi]);
        const float tg = __uint_as_float(lo[qi]);
        const unsigned int eb = lo[qi] - 1u;
#pragma unroll
        for (int c = 0; c < 2; c++)
#pragma unroll
            for (int j = 0; j < 4; j++) {
                const float v = acc[c][j][qi];
                const bool sel_ = (v >= tg)
                                | (allties & (__float_as_uint(v) == eb));
                if (sel_) {
                    const int k = 2048 * c + 4 * tid + j;
                    atomicOr(&bitmap[qi][k >> 5], 1u << (k & 31));
                }
            }
    }

    // Rare exact-tie path: pick the `need` smallest-k ties ascending
    // (k = 2048c + 4t + j increases lexicographically in (c, t, j)).
#pragma unroll 1
    for (int qi = 0; qi < TQ; qi++) {
        if (T[qi] > need[qi]) {
            const unsigned int eb = lo[qi] - 1u;
            unsigned int m16 = 0u;
#pragma unroll
            for (int c = 0; c < 2; c++)
#pragma unroll
                for (int j = 0; j < 4; j++)
                    if (__float_as_uint(acc[c][j][qi]) == eb)
                        m16 |= 1u << (c * 4 + j);
            tm[tid] = (unsigned short)m16;
            __syncthreads();
            if (tid == 0) {
                int taken = 0;
                for (int c = 0; c < 2 && taken < need[qi]; c++)
                    for (int t = 0; t < 512 && taken < need[qi]; t++) {
                        const unsigned int nib = ((unsigned int)tm[t] >> (c * 4)) & 15u;
                        for (int j = 0; j < 4 && taken < need[qi]; j++)
                            if ((nib >> j) & 1u) {
                                const int k = 2048 * c + 4 * t + j;
                                atomicOr(&bitmap[qi][k >> 5], 1u << (k & 31));
                                taken++;
                            }
                    }
            }
            __syncthreads();
        }
    }

    // ---- local window: 16 scores per query, stable top-ks -> bitmap ---------
    if (tid < TQ * LW) {
        int qi = tid >> 4, wnd = tid & 15;
        int q = q0 + qi;
        int win = q - (LW - 1) + wnd;
        float v = NEG_INF;
        if (win >= 0) {
            const float4* kr = (const float4*)(lfb + (long)win * ID);
            float s = 0.f;
#pragma unroll
            for (int d = 0; d < 16; d++) {
                float4 kvv = kr[d];
                const float4 qd = *(const float4*)&lq[qi][d * 4];
                s = fmaf(kvv.x, qd.x, s); s = fmaf(kvv.y, qd.y, s);
                s = fmaf(kvv.z, qd.z, s); s = fmaf(kvv.w, qd.w, s);
            }
            v = fmaxf(s, 0.f);
        }
        lsc[qi][wnd] = v;
    }
    __syncthreads();
    if (tid < TQ) {
        int qi = tid, q = q0 + qi;
        int L = (q + 1 < LW) ? q + 1 : LW;
        int ks = L / 5; if (ks < 1) ks = 1;   // == max(1, int(L*0.2))
        for (int t = 0; t < ks; t++) {
            float best = NEG_INF; int bi = 0;
            for (int wnd = 0; wnd < LW; wnd++) {
                float v = lsc[qi][wnd];
                if (v > best) { best = v; bi = wnd; }  // strict > keeps lowest idx
            }
            lsc[qi][bi] = NEG_INF;
            const int win = q - (LW - 1) + bi;
            atomicOr(&bitmap[qi][win >> 5], 1u << (win & 31));
        }
    }
    __syncthreads();

    // ---- output: single-pass fill from bitmap (each line written once) ------
    uint4* orow = (uint4*)(out + ((long)b * SEQ + q0) * SEQ);
#pragma unroll
    for (int i = 0; i < TQ * SEQ / 8 / 512; i++) {  // 4 iters, 2048 uint4
        const int li = i * 512 + tid;
        const int qi = li >> 9;          // 512 uint4 per row
        const int w8 = li & 511;         // cols 8*w8 .. 8*w8+7
        const unsigned int bits =
            (bitmap[qi][w8 >> 2] >> ((w8 & 3) * 8)) & 0xFFu;
        uint4 v;
        v.x = MASKED4 & ~(((bits &   1u) ? 0x0000FFFFu : 0u) |
                          ((bits &   2u) ? 0xFFFF0000u : 0u));
        v.y = MASKED4 & ~(((bits &   4u) ? 0x0000FFFFu : 0u) |
                          ((bits &   8u) ? 0xFFFF0000u : 0u));
        v.z = MASKED4 & ~(((bits &  16u) ? 0x0000FFFFu : 0u) |
                          ((bits &  32u) ? 0xFFFF0000u : 0u));
        v.w = MASKED4 & ~(((bits &  64u) ? 0x0000FFFFu : 0u) |
                          ((bits & 128u) ? 0xFFFF0000u : 0u));
        orow[li] = v;
    }
}

extern "C" void kernel_launch(void* const* d_in, const int* in_sizes, int n_in,
                              void* d_out, int out_size, void* d_ws, size_t ws_size,
                              hipStream_t stream) {
    const unsigned short* x  = (const unsigned short*)d_in[0];
    const unsigned short* Wl = (const unsigned short*)d_in[1];
    // d_in[2] = W_medium: dead in the reference — skipped.
    const unsigned short* Wg = (const unsigned short*)d_in[3];
    unsigned short* out = (unsigned short*)d_out;

    float* lf  = (float*)d_ws;                        // 4 MiB, row-major
    float* gfT = lf + (long)FMAT;                     // 4 MiB, [b][d][s]

    hp_feat_v10<<<(NB * SEQ / 64) * 2, 256, 0, stream>>>(x, Wl, Wg, lf, gfT);
    hp_mask_v10<<<NB * SEQ / TQ, 512, 0, stream>>>(lf, gfT, out);
}

// Round 4
// 735.331 us; speedup vs baseline: 1.0739x; 1.0247x over previous
//
// HierarchicalPattern — rev11. R10 post-mortem: mask VGPR_Count=44 < the ~60
// live regs (acc[32]+loads+broadcast) while VALUBusy*dur = ~21K VALU-cyc/wave
// vs ~7K needed, WRITE_SIZE exactly = output (no scratch) -> allocator is
// capping arch VGPRs for occupancy and shuttling acc through AGPRs
// (v_accvgpr_read/write = 1 extra VALU per touch, the persistent ~3x VALU
// inflation across R8-R10). Fix: __launch_bounds__(512, 2) -> ~256-reg budget,
// acc stays in arch VGPRs. feat: 512 blocks = 2 waves/SIMD latency-starved;
// now per-wave 16-row x 32-col tasks (1024 blocks x 4 waves = 4 waves/SIMD),
// block's 4 waves share x rows (L1 reuse). Bisection: early-break was dead
// (width halves deterministically) -> fixed 31 trials, conv check deleted.
// Phase-1 batches 8 VMEM + 4 LDS-float4 loads per 4-d chunk ahead of 128 FMA.
#include <hip/hip_runtime.h>
#include <hip/hip_fp16.h>
#include <cstdint>

#define SEQ 4096
#define NB 4
#define DMODEL 1024
#define ID 64
#define LW 16
#define GK 32
#define TQ 4

#define NEG_INF (-__builtin_inff())
#define MASKED4 0xFBFFFBFFu
#define FMAT (NB * SEQ * ID)          // floats per feature matrix (4 MiB)

typedef _Float16 f16x8 __attribute__((ext_vector_type(8)));
typedef float f32x4 __attribute__((ext_vector_type(4)));

// ---------------- Kernel 1: lf + gfT via MFMA (fp16 in, f32 out) -------------
// grid 1024 x 256thr. Block = one 16-row tile of x; wave w = {target, colhalf}:
// half = w&1 (0=lf,1=gfT), ch = w>>1. All 4 waves read the SAME x rows -> L1
// reuse. Per wave: 2 col-tiles (32 cols), K=1024 in 32-steps = 64 MFMA.
// A-frag: lane l reads x[row0+(l&15)][k0+(l>>4)*8..+8)   (16B)
// B-frag: lane l reads W[ch*32+ct*16+(l&15)][k0+(l>>4)*8..+8)
// D: col=l&15, row=(l>>4)*4+reg (verified v10) -> gfT float4 along s.
__global__ __launch_bounds__(256)
void hp_feat_v11(const unsigned short* __restrict__ xu,
                 const unsigned short* __restrict__ Wlu,
                 const unsigned short* __restrict__ Wgu,
                 float* __restrict__ lf, float* __restrict__ gfT)
{
    const int tid = threadIdx.x;
    const int lane = tid & 63, w = tid >> 6;
    const long row0 = (long)blockIdx.x * 16;
    const int half = w & 1;
    const int ch = w >> 1;
    const _Float16* xp = (const _Float16*)xu;
    const _Float16* Wp = (const _Float16*)(half ? Wgu : Wlu);

    const int lr = lane & 15;          // row-in-tile (A) / col-in-tile (B,D)
    const int kg = lane >> 4;          // k-group: k offset kg*8

    const _Float16* ap = xp + (row0 + lr) * DMODEL + kg * 8;
    const _Float16* bp = Wp + (long)(ch * 32 + lr) * DMODEL + kg * 8;

    f32x4 acc0 = (f32x4){0.f, 0.f, 0.f, 0.f};
    f32x4 acc1 = (f32x4){0.f, 0.f, 0.f, 0.f};

#pragma unroll 4
    for (int k0 = 0; k0 < DMODEL; k0 += 32) {
        f16x8 av = *(const f16x8*)(ap + k0);
        f16x8 b0 = *(const f16x8*)(bp + k0);
        f16x8 b1 = *(const f16x8*)(bp + 16 * DMODEL + k0);
        acc0 = __builtin_amdgcn_mfma_f32_16x16x32_f16(av, b0, acc0, 0, 0, 0);
        acc1 = __builtin_amdgcn_mfma_f32_16x16x32_f16(av, b1, acc1, 0, 0, 0);
    }

    if (!half) {        // lf[s][d]
#pragma unroll
        for (int r = 0; r < 4; r++) {
            lf[(row0 + kg * 4 + r) * ID + ch * 32 + lr]      = acc0[r];
            lf[(row0 + kg * 4 + r) * ID + ch * 32 + 16 + lr] = acc1[r];
        }
    } else {            // gfT[b][d][s]: float4 along s
        const int bb = (int)(row0 >> 12), s0 = (int)(row0 & 4095);
        float4 st0 = make_float4(acc0[0], acc0[1], acc0[2], acc0[3]);
        float4 st1 = make_float4(acc1[0], acc1[1], acc1[2], acc1[3]);
        *(float4*)(gfT + ((long)bb * ID + ch * 32 + lr) * SEQ + s0 + kg * 4) = st0;
        *(float4*)(gfT + ((long)bb * ID + ch * 32 + 16 + lr) * SEQ + s0 + kg * 4) = st1;
    }
}

// ---------------- Kernel 2: 512 threads, TQ=4 queries, 8 keys/thread ---------
// launch_bounds(512,2): budget ~256 VGPR/wave -> acc in arch VGPRs, no AGPR
// shuffle. Phase 1: 4-d chunks, 8 VMEM + 4 LDS-float4 batched before 128 FMA.
// Phase 2: float-domain bisection (R9/R10 semantics, verified), 31 fixed
// trials. Bitmap output (R8 semantics, verified).
__global__ __launch_bounds__(512, 2)
void hp_mask_v11(const float* __restrict__ lf, const float* __restrict__ gfT,
                 unsigned short* __restrict__ out)
{
    __shared__ float qv[TQ][ID];
    __shared__ float lq[TQ][ID];
    __shared__ unsigned long long red[4][8];      // [slot][wave]; 4x u16 counts
    __shared__ unsigned int bitmap[TQ][SEQ / 32]; // 2 KiB selection bitmap
    __shared__ float lsc[TQ][LW];
    __shared__ unsigned short tm[512];            // rare tie path

    const int tid = threadIdx.x;
    const int lane = tid & 63, w = tid >> 6;      // 8 waves
    const int bq = blockIdx.x;            // b*(SEQ/TQ) + qgroup
    const int b = bq >> 10;
    const int q0 = (bq & 1023) * TQ;
    const float* gTb = gfT + (long)b * ID * SEQ;
    const float* lfb = lf + (long)b * SEQ * ID;

    if (tid < 256) {   // qv[qi][d] = gfT[b][d][q0+qi]; lq from lf rows
        int d = tid >> 2, qi = tid & 3;
        qv[qi][d] = gTb[(long)d * SEQ + q0 + qi];
        int qi2 = tid >> 6, d2 = tid & 63;
        lq[qi2][d2] = lfb[(long)(q0 + qi2) * ID + d2];
    }
    ((unsigned int*)bitmap)[tid] = 0u;            // 512 words exactly
    __syncthreads();

    // ---- Phase 1: register-resident scores ----------------------------------
    float acc[2][4][TQ];                  // [c][j][qi]
#pragma unroll
    for (int c = 0; c < 2; c++)
#pragma unroll
        for (int j = 0; j < 4; j++)
#pragma unroll
            for (int qi = 0; qi < TQ; qi++) acc[c][j][qi] = 0.f;

    const float4* gT4 = (const float4*)gTb;
#pragma unroll 1
    for (int d0 = 0; d0 < ID; d0 += 4) {
        float4 ka[4], kb[4], qd4[TQ];
#pragma unroll
        for (int dd = 0; dd < 4; dd++) {
            ka[dd] = gT4[((d0 + dd) << 10) + tid];
            kb[dd] = gT4[((d0 + dd) << 10) + 512 + tid];
        }
#pragma unroll
        for (int qi = 0; qi < TQ; qi++)
            qd4[qi] = *(const float4*)&qv[qi][d0];
#pragma unroll
        for (int dd = 0; dd < 4; dd++) {
#pragma unroll
            for (int qi = 0; qi < TQ; qi++) {
                const float qd = ((const float*)&qd4[qi])[dd];
                acc[0][0][qi] = fmaf(ka[dd].x, qd, acc[0][0][qi]);
                acc[0][1][qi] = fmaf(ka[dd].y, qd, acc[0][1][qi]);
                acc[0][2][qi] = fmaf(ka[dd].z, qd, acc[0][2][qi]);
                acc[0][3][qi] = fmaf(ka[dd].w, qd, acc[0][3][qi]);
                acc[1][0][qi] = fmaf(kb[dd].x, qd, acc[1][0][qi]);
                acc[1][1][qi] = fmaf(kb[dd].y, qd, acc[1][1][qi]);
                acc[1][2][qi] = fmaf(kb[dd].z, qd, acc[1][2][qi]);
                acc[1][3][qi] = fmaf(kb[dd].w, qd, acc[1][3][qi]);
            }
        }
    }

    // ---- Phase 2a: in-place keys: sv = banned ? -1 : relu(s) ----------------
#pragma unroll
    for (int c = 0; c < 2; c++)
#pragma unroll
        for (int j = 0; j < 4; j++) {
            const int k = 2048 * c + 4 * tid + j;
#pragma unroll
            for (int qi = 0; qi < TQ; qi++) {
                const int q = q0 + qi;
                const bool banned = (k <= q) && (k >= q - (LW - 1));
                acc[c][j][qi] = banned ? -1.0f : fmaxf(acc[c][j][qi], 0.f);
            }
        }

    // ---- Phase 2b: bisection for m32 in u-space, compares in float ----------
    // 31 trials close the 0x7F800000 range to width <= 1 (0x7F800000>>31 == 0).
    unsigned int lo[TQ], hi[TQ];
#pragma unroll
    for (int qi = 0; qi < TQ; qi++) { lo[qi] = 0u; hi[qi] = 0x7F800000u; }

#pragma unroll 1
    for (int it = 0; it < 31; ++it) {
        unsigned long long pc = 0ull;
#pragma unroll
        for (int qi = 0; qi < TQ; qi++) {
            const unsigned int mid = lo[qi] + ((hi[qi] - lo[qi]) >> 1);
            const float tf = __uint_as_float(mid - 1u);
            int cnt = 0;
#pragma unroll
            for (int c = 0; c < 2; c++)
#pragma unroll
                for (int j = 0; j < 4; j++)
                    cnt += __popcll(__ballot(acc[c][j][qi] >= tf));
            pc |= (unsigned long long)(unsigned int)cnt << (16 * qi);
        }
        if (lane == 0) red[it & 1][w] = pc;
        __syncthreads();
        unsigned long long tot = 0ull;
#pragma unroll
        for (int ww = 0; ww < 8; ww++) tot += red[it & 1][ww];
#pragma unroll
        for (int qi = 0; qi < TQ; qi++) {
            const unsigned int mid = lo[qi] + ((hi[qi] - lo[qi]) >> 1);
            const unsigned int cnt =
                (unsigned int)((tot >> (16 * qi)) & 0xFFFFull);
            if (cnt >= GK) lo[qi] = mid; else hi[qi] = mid;
        }
    }

    // ---- Phase 2c: C1 = #{u > m32}, T = #{u == m32} -------------------------
    int T[TQ], need[TQ];
    {
        unsigned long long pg = 0ull, pe = 0ull;
#pragma unroll
        for (int qi = 0; qi < TQ; qi++) {
            const float tg = __uint_as_float(lo[qi]);   // u>lo <=> sv>=float(lo)
            const unsigned int eb = lo[qi] - 1u;        // u==lo <=> bits(sv)==eb
            int cg = 0, ce = 0;
#pragma unroll
            for (int c = 0; c < 2; c++)
#pragma unroll
                for (int j = 0; j < 4; j++) {
                    const float v = acc[c][j][qi];
                    cg += __popcll(__ballot(v >= tg));
                    ce += __popcll(__ballot(__float_as_uint(v) == eb));
                }
            pg |= (unsigned long long)(unsigned int)cg << (16 * qi);
            pe |= (unsigned long long)(unsigned int)ce << (16 * qi);
        }
        if (lane == 0) { red[2][w] = pg; red[3][w] = pe; }
        __syncthreads();
        unsigned long long tg = 0ull, te = 0ull;
#pragma unroll
        for (int ww = 0; ww < 8; ww++) { tg += red[2][ww]; te += red[3][ww]; }
#pragma unroll
        for (int qi = 0; qi < TQ; qi++) {
            const int c1 = (int)((tg >> (16 * qi)) & 0xFFFFull);
            T[qi]    = (int)((te >> (16 * qi)) & 0xFFFFull);
            need[qi] = GK - c1;               // >= 1; T >= need guaranteed
        }
    }

    // ---- Phase 2d: mark selections in bitmap --------------------------------
#pragma unroll
    for (int qi = 0; qi < TQ; qi++) {
        const bool allties = (T[qi] == need[qi]);
        const float tg = __uint_as_float(lo[qi]);
        const unsigned int eb = lo[qi] - 1u;
#pragma unroll
        for (int c = 0; c < 2; c++)
#pragma unroll
            for (int j = 0; j < 4; j++) {
                const float v = acc[c][j][qi];
                const bool sel_ = (v >= tg)
                                | (allties & (__float_as_uint(v) == eb));
                if (sel_) {
                    const int k = 2048 * c + 4 * tid + j;
                    atomicOr(&bitmap[qi][k >> 5], 1u << (k & 31));
                }
            }
    }

    // Rare exact-tie path: pick the `need` smallest-k ties ascending
    // (k = 2048c + 4t + j increases lexicographically in (c, t, j)).
#pragma unroll 1
    for (int qi = 0; qi < TQ; qi++) {
        if (T[qi] > need[qi]) {
            const unsigned int eb = lo[qi] - 1u;
            unsigned int m16 = 0u;
#pragma unroll
            for (int c = 0; c < 2; c++)
#pragma unroll
                for (int j = 0; j < 4; j++)
                    if (__float_as_uint(acc[c][j][qi]) == eb)
                        m16 |= 1u << (c * 4 + j);
            tm[tid] = (unsigned short)m16;
            __syncthreads();
            if (tid == 0) {
                int taken = 0;
                for (int c = 0; c < 2 && taken < need[qi]; c++)
                    for (int t = 0; t < 512 && taken < need[qi]; t++) {
                        const unsigned int nib = ((unsigned int)tm[t] >> (c * 4)) & 15u;
                        for (int j = 0; j < 4 && taken < need[qi]; j++)
                            if ((nib >> j) & 1u) {
                                const int k = 2048 * c + 4 * t + j;
                                atomicOr(&bitmap[qi][k >> 5], 1u << (k & 31));
                                taken++;
                            }
                    }
            }
            __syncthreads();
        }
    }

    // ---- local window: 16 scores per query, stable top-ks -> bitmap ---------
    if (tid < TQ * LW) {
        int qi = tid >> 4, wnd = tid & 15;
        int q = q0 + qi;
        int win = q - (LW - 1) + wnd;
        float v = NEG_INF;
        if (win >= 0) {
            const float4* kr = (const float4*)(lfb + (long)win * ID);
            float s = 0.f;
#pragma unroll
            for (int d = 0; d < 16; d++) {
                float4 kvv = kr[d];
                const float4 qd = *(const float4*)&lq[qi][d * 4];
                s = fmaf(kvv.x, qd.x, s); s = fmaf(kvv.y, qd.y, s);
                s = fmaf(kvv.z, qd.z, s); s = fmaf(kvv.w, qd.w, s);
            }
            v = fmaxf(s, 0.f);
        }
        lsc[qi][wnd] = v;
    }
    __syncthreads();
    if (tid < TQ) {
        int qi = tid, q = q0 + qi;
        int L = (q + 1 < LW) ? q + 1 : LW;
        int ks = L / 5; if (ks < 1) ks = 1;   // == max(1, int(L*0.2))
        for (int t = 0; t < ks; t++) {
            float best = NEG_INF; int bi = 0;
            for (int wnd = 0; wnd < LW; wnd++) {
                float v = lsc[qi][wnd];
                if (v > best) { best = v; bi = wnd; }  // strict > keeps lowest idx
            }
            lsc[qi][bi] = NEG_INF;
            const int win = q - (LW - 1) + bi;
            atomicOr(&bitmap[qi][win >> 5], 1u << (win & 31));
        }
    }
    __syncthreads();

    // ---- output: single-pass fill from bitmap (each line written once) ------
    uint4* orow = (uint4*)(out + ((long)b * SEQ + q0) * SEQ);
#pragma unroll
    for (int i = 0; i < TQ * SEQ / 8 / 512; i++) {  // 4 iters, 2048 uint4
        const int li = i * 512 + tid;
        const int qi = li >> 9;          // 512 uint4 per row
        const int w8 = li & 511;         // cols 8*w8 .. 8*w8+7
        const unsigned int bits =
            (bitmap[qi][w8 >> 2] >> ((w8 & 3) * 8)) & 0xFFu;
        uint4 v;
        v.x = MASKED4 & ~(((bits &   1u) ? 0x0000FFFFu : 0u) |
                          ((bits &   2u) ? 0xFFFF0000u : 0u));
        v.y = MASKED4 & ~(((bits &   4u) ? 0x0000FFFFu : 0u) |
                          ((bits &   8u) ? 0xFFFF0000u : 0u));
        v.z = MASKED4 & ~(((bits &  16u) ? 0x0000FFFFu : 0u) |
                          ((bits &  32u) ? 0xFFFF0000u : 0u));
        v.w = MASKED4 & ~(((bits &  64u) ? 0x0000FFFFu : 0u) |
                          ((bits & 128u) ? 0xFFFF0000u : 0u));
        orow[li] = v;
    }
}

extern "C" void kernel_launch(void* const* d_in, const int* in_sizes, int n_in,
                              void* d_out, int out_size, void* d_ws, size_t ws_size,
                              hipStream_t stream) {
    const unsigned short* x  = (const unsigned short*)d_in[0];
    const unsigned short* Wl = (const unsigned short*)d_in[1];
    // d_in[2] = W_medium: dead in the reference — skipped.
    const unsigned short* Wg = (const unsigned short*)d_in[3];
    unsigned short* out = (unsigned short*)d_out;

    float* lf  = (float*)d_ws;                        // 4 MiB, row-major
    float* gfT = lf + (long)FMAT;                     // 4 MiB, [b][d][s]

    hp_feat_v11<<<NB * SEQ / 16, 256, 0, stream>>>(x, Wl, Wg, lf, gfT);
    hp_mask_v11<<<NB * SEQ / TQ, 512, 0, stream>>>(lf, gfT, out);
}